// Round 4
// baseline (287.756 us; speedup 1.0000x reference)
//
#include <hip/hip_runtime.h>
#include <cstddef>

// Problem constants: N=16, C=64, T=512, V=25, kernel=9, stride=2
#define N_  16
#define C_  64
#define T_  512
#define V_  25
#define S_  256
#define M_  (T_ * V_)      // 12800
#define RS_ (V_ * C_)      // 1600 floats between consecutive t rows of xp[n][t][v][d]

typedef short s16x4 __attribute__((ext_vector_type(4)));
typedef float f32x4 __attribute__((ext_vector_type(4)));

// ---- MFMA 16x16x16 bf16 (D = A*B + C); A = first operand (rows), B = cols ----
__device__ __forceinline__ f32x4 mfma16(s16x4 a, s16x4 b, f32x4 c) {
#if __has_builtin(__builtin_amdgcn_mfma_f32_16x16x16_bf16)
    return __builtin_amdgcn_mfma_f32_16x16x16_bf16(a, b, c, 0, 0, 0);
#elif __has_builtin(__builtin_amdgcn_mfma_f32_16x16x16bf16_1k)
    return __builtin_amdgcn_mfma_f32_16x16x16bf16_1k(a, b, c, 0, 0, 0);
#else
    asm volatile("v_mfma_f32_16x16x16_bf16 %0, %1, %2, %0" : "+v"(c) : "v"(a), "v"(b));
    return c;
#endif
}

// fp32 -> (bf16 hi, bf16 lo) split; packed as u32 = hi | (lo << 16)
__device__ __forceinline__ unsigned packhl(float f) {
    unsigned fb = __float_as_uint(f);
    float hf = __uint_as_float(fb & 0xffff0000u);
    unsigned lb = __float_as_uint(f - hf);
    return (fb >> 16) | (lb & 0xffff0000u);
}
__device__ __forceinline__ unsigned short bhi(float f) {
    return (unsigned short)(__float_as_uint(f) >> 16);
}
__device__ __forceinline__ unsigned short blo(float f) {
    unsigned fb = __float_as_uint(f);
    float hf = __uint_as_float(fb & 0xffff0000u);
    return (unsigned short)(__float_as_uint(f - hf) >> 16);
}
__device__ __forceinline__ s16x4 hi4(uint4 q) {
    return s16x4{(short)(q.x & 0xffffu), (short)(q.y & 0xffffu),
                 (short)(q.z & 0xffffu), (short)(q.w & 0xffffu)};
}
__device__ __forceinline__ s16x4 lo4(uint4 q) {
    return s16x4{(short)(q.x >> 16), (short)(q.y >> 16),
                 (short)(q.z >> 16), (short)(q.w >> 16)};
}
__device__ __forceinline__ s16x4 mk_hi(float a, float b, float c, float d) {
    return s16x4{(short)bhi(a), (short)bhi(b), (short)bhi(c), (short)bhi(d)};
}
__device__ __forceinline__ s16x4 mk_lo(float a, float b, float c, float d) {
    return s16x4{(short)blo(a), (short)blo(b), (short)blo(c), (short)blo(d)};
}

// -----------------------------------------------------------------------------
// Kernel A: xp[n][m][d] = sum_c x[n][c][m] * W[c][d] via bf16x3 MFMA.
// -----------------------------------------------------------------------------
__global__ __launch_bounds__(256, 4) void xp_gemm_kernel(
    const float* __restrict__ x, const float* __restrict__ W,
    float* __restrict__ xp)
{
    const int tid = threadIdx.x, lane = tid & 63, wid = tid >> 6;
    const int l15 = lane & 15, oct = lane >> 4;
    const int n = blockIdx.y;
    const int m0 = blockIdx.x * 256 + wid * 64;
    const float* xb = x + (size_t)n * C_ * M_;

    f32x4 acc[4][4];
    #pragma unroll
    for (int mt = 0; mt < 4; ++mt)
        #pragma unroll
        for (int dt = 0; dt < 4; ++dt) acc[mt][dt] = f32x4{0.f, 0.f, 0.f, 0.f};

    #pragma unroll
    for (int kc = 0; kc < 4; ++kc) {
        const int c0 = kc * 16 + oct * 4;
        s16x4 bh[4], bl[4];
        #pragma unroll
        for (int dt = 0; dt < 4; ++dt) {
            const float* wb = W + (size_t)c0 * C_ + dt * 16 + l15;
            float w0 = wb[0], w1 = wb[C_], w2 = wb[2 * C_], w3 = wb[3 * C_];
            bh[dt] = mk_hi(w0, w1, w2, w3);
            bl[dt] = mk_lo(w0, w1, w2, w3);
        }
        #pragma unroll
        for (int mt = 0; mt < 4; ++mt) {
            const float* xc = xb + (size_t)c0 * M_ + m0 + mt * 16 + l15;
            float x0 = xc[0], x1 = xc[M_], x2 = xc[2 * (size_t)M_], x3 = xc[3 * (size_t)M_];
            s16x4 ah = mk_hi(x0, x1, x2, x3);
            s16x4 al = mk_lo(x0, x1, x2, x3);
            #pragma unroll
            for (int dt = 0; dt < 4; ++dt) {
                acc[mt][dt] = mfma16(ah, bh[dt], acc[mt][dt]);
                acc[mt][dt] = mfma16(ah, bl[dt], acc[mt][dt]);
                acc[mt][dt] = mfma16(al, bh[dt], acc[mt][dt]);
            }
        }
    }
    float* ob = xp + ((size_t)n * M_ + m0) * C_;
    #pragma unroll
    for (int mt = 0; mt < 4; ++mt)
        #pragma unroll
        for (int dt = 0; dt < 4; ++dt)
            #pragma unroll
            for (int r = 0; r < 4; ++r)
                ob[(size_t)(mt * 16 + oct * 4 + r) * C_ + dt * 16 + l15] = acc[mt][dt][r];
}

// -----------------------------------------------------------------------------
// Kernel B: MFMA attention, P kept in registers (QK D-frag == PV A-frag layout).
// One block per (n,v), 512 threads = 8 waves; wave owns 32 s.
// LDS (u32 offsets): X[2][64 d][36 t] @0 (4608), KK[2][32 t][20 e] @4608 (1280),
// phiT @5888 (1088), alT @6976 (1088); Q[256 s][20] prologue-aliases @0..5120.
// Total 8064 u32 = 32,256 B -> 4 blocks/CU.
// -----------------------------------------------------------------------------
__global__ __launch_bounds__(512, 4) void attn_kernel(
    const float* __restrict__ xp, const float* __restrict__ alpha,
    const float* __restrict__ phi, float* __restrict__ tmp)
{
    __shared__ unsigned smem[8064];
    unsigned* Xu  = smem;                 // [2][64][36]
    unsigned* KKu = smem + 4608;          // [2][32][20]
    float* phiT = (float*)(smem + 5888);  // [16 e][68 c]
    float* alT  = (float*)(smem + 6976);  // [16 e][68 c] (x 1/16 folded)
    unsigned* Qu  = smem;                 // [256 s][20] (prologue only)

    const int tid = threadIdx.x;
    const int lane = tid & 63;
    const int wid = tid >> 6;
    const int l15 = lane & 15;
    const int oct = lane >> 4;
    const int nv = blockIdx.x;
    const int n = nv / V_, v = nv - n * V_;
    const float* xpb = xp + (size_t)n * M_ * C_ + (size_t)v * C_;

    // ---- phase A: stage alT (x 1/16) + phiT ----
    for (int i = tid; i < 1024; i += 512) {
        int c = i >> 4, e = i & 15;
        alT[e * 68 + c]  = alpha[i] * 0.0625f;
        phiT[e * 68 + c] = phi[i];
    }
    __syncthreads();

    // ---- phase B: q-dots (fp32) -> packed Q_lds ----
    {
        int s = tid >> 1, eh = tid & 1;
        const float* xr = xpb + (size_t)(2 * s) * RS_;
        const float* ab = alT + (eh * 8) * 68;
        float qa[8] = {0.f, 0.f, 0.f, 0.f, 0.f, 0.f, 0.f, 0.f};
        #pragma unroll
        for (int c4 = 0; c4 < 16; ++c4) {
            float4 xv = *(const float4*)(xr + c4 * 4);
            #pragma unroll
            for (int j = 0; j < 8; ++j) {
                float4 av = *(const float4*)(ab + j * 68 + c4 * 4);
                qa[j] += xv.x * av.x + xv.y * av.y + xv.z * av.z + xv.w * av.w;
            }
        }
        unsigned* qp = Qu + s * 20 + eh * 8;
        *(uint4*)(qp)     = uint4{packhl(qa[0]), packhl(qa[1]), packhl(qa[2]), packhl(qa[3])};
        *(uint4*)(qp + 4) = uint4{packhl(qa[4]), packhl(qa[5]), packhl(qa[6]), packhl(qa[7])};
    }
    __syncthreads();

    // ---- phase C: Q fragments (B-frag: col s=l15, k e=oct*4+j) ----
    const int s0w = wid * 32;
    s16x4 qh[2], ql[2];
    #pragma unroll
    for (int st = 0; st < 2; ++st) {
        uint4 qv = *(const uint4*)(Qu + (size_t)(s0w + st * 16 + l15) * 20 + oct * 4);
        qh[st] = hi4(qv); ql[st] = lo4(qv);
    }
    __syncthreads();   // Q region reused by X below

    // ---- staging helpers ----
    auto STAGE = [&](int ch, int buf) {
        // thread (d = tid&63, tq = tid>>6): 4 coalesced global loads, 1 uint4 write
        int d = tid & 63, tq = tid >> 6;
        const float* col = xpb + (size_t)(ch * 32 + tq * 4) * RS_ + d;
        unsigned u0 = packhl(col[0]);
        unsigned u1 = packhl(col[RS_]);
        unsigned u2 = packhl(col[2 * RS_]);
        unsigned u3 = packhl(col[3 * RS_]);
        *(uint4*)(Xu + buf * 2304 + d * 36 + tq * 4) = uint4{u0, u1, u2, u3};
    };
    auto KKDOTS = [&](int ch, int buf) {
        int t = tid & 31, e = tid >> 5;
        const float* xr = xpb + (size_t)(ch * 32 + t) * RS_;
        const float* pb = phiT + e * 68;
        float a = 0.f;
        #pragma unroll
        for (int c4 = 0; c4 < 16; ++c4) {
            float4 xv = *(const float4*)(xr + c4 * 4);
            float4 pv = *(const float4*)(pb + c4 * 4);
            a += xv.x * pv.x + xv.y * pv.y + xv.z * pv.z + xv.w * pv.w;
        }
        KKu[buf * 640 + t * 20 + e] = packhl(a);
    };

    STAGE(0, 0); KKDOTS(0, 0);
    __syncthreads();

    f32x4 acc[2][4];
    #pragma unroll
    for (int st = 0; st < 2; ++st)
        #pragma unroll
        for (int dt = 0; dt < 4; ++dt) acc[st][dt] = f32x4{0.f, 0.f, 0.f, 0.f};
    float lp[2] = {0.f, 0.f};

    for (int c = 0; c < 16; ++c) {
        const int cur = c & 1;
        if (c < 15) { STAGE(c + 1, cur ^ 1); KKDOTS(c + 1, cur ^ 1); }
        const unsigned* Xb = Xu + cur * 2304;
        const unsigned* Kb = KKu + cur * 640;

        #pragma unroll
        for (int kt = 0; kt < 2; ++kt) {
            // QK tile tt = kt (swapped: A=KK -> rows t, B=Q -> cols s)
            uint4 kf = *(const uint4*)(Kb + (kt * 16 + l15) * 20 + oct * 4);
            s16x4 kh = hi4(kf), kl = lo4(kf);
            s16x4 ph[2], pl[2];
            #pragma unroll
            for (int st = 0; st < 2; ++st) {
                f32x4 dqk = {0.f, 0.f, 0.f, 0.f};
                dqk = mfma16(kh, qh[st], dqk);
                dqk = mfma16(kh, ql[st], dqk);
                dqk = mfma16(kl, qh[st], dqk);
                float p0 = __expf(dqk[0]), p1 = __expf(dqk[1]);
                float p2 = __expf(dqk[2]), p3 = __expf(dqk[3]);
                lp[st] += (p0 + p1) + (p2 + p3);
                // D-frag (t=oct*4+r, s=l15) == PV A-frag (s=l15, t=oct*4+j)
                ph[st] = mk_hi(p0, p1, p2, p3);
                pl[st] = mk_lo(p0, p1, p2, p3);
            }
            // PV k-tile kt: B = X[t][d] read from [d][t] plane
            #pragma unroll
            for (int dt = 0; dt < 4; ++dt) {
                uint4 xf = *(const uint4*)(Xb + (dt * 16 + l15) * 36 + kt * 16 + oct * 4);
                s16x4 xh = hi4(xf), xl = lo4(xf);
                #pragma unroll
                for (int st = 0; st < 2; ++st) {
                    acc[st][dt] = mfma16(ph[st], xh, acc[st][dt]);
                    acc[st][dt] = mfma16(ph[st], xl, acc[st][dt]);
                    acc[st][dt] = mfma16(pl[st], xh, acc[st][dt]);
                }
            }
        }
        __syncthreads();
    }

    // ---- epilogue: reduce l over oct (t-slices), normalize, store ----
    #pragma unroll
    for (int st = 0; st < 2; ++st) {
        lp[st] += __shfl_xor(lp[st], 16);
        lp[st] += __shfl_xor(lp[st], 32);
    }
    float* ob = tmp + (size_t)nv * S_ * C_;
    #pragma unroll
    for (int st = 0; st < 2; ++st) {
        float rl[4];
        #pragma unroll
        for (int r = 0; r < 4; ++r)
            rl[r] = 1.0f / __shfl(lp[st], (lane & 48) | (oct * 4 + r));
        #pragma unroll
        for (int dt = 0; dt < 4; ++dt)
            #pragma unroll
            for (int r = 0; r < 4; ++r) {
                int s = s0w + st * 16 + oct * 4 + r;
                ob[(size_t)s * C_ + dt * 16 + l15] = acc[st][dt][r] * rl[r];
            }
    }
}

// -----------------------------------------------------------------------------
// Kernel C: band + transpose.  tmp[n][v][s][d] + band -> out[n][d][s][v].
// -----------------------------------------------------------------------------
__global__ __launch_bounds__(256) void final_kernel(
    const float* __restrict__ tmp, const float* __restrict__ xp,
    const float* __restrict__ kband, float* __restrict__ out)
{
    __shared__ float lt[V_ * 8 * 65];
    __shared__ float kbl[9];
    const int tid = threadIdx.x;
    const int b = blockIdx.x;
    const int n = b >> 5, st = b & 31, s0 = st * 8;
    if (tid < 9) kbl[tid] = kband[tid];
    __syncthreads();

    const float* tb = tmp + ((size_t)n * V_ * S_ + s0) * C_;
    const float* xb = xp + (size_t)n * M_ * C_;
    for (int i = tid; i < V_ * 8 * 16; i += 256) {
        int vv = i >> 7, r = i & 127;
        int si = r >> 4, c4 = (r & 15) * 4;
        int s = s0 + si;
        float4 val = *(const float4*)(tb + ((size_t)vv * S_ + si) * C_ + c4);
        #pragma unroll
        for (int j = 0; j < 9; ++j) {
            int t = 2 * s + j - 4;
            if ((unsigned)t < (unsigned)T_) {
                float kb = kbl[j];
                float4 xv = *(const float4*)(xb + ((size_t)t * V_ + vv) * C_ + c4);
                val.x += kb * xv.x; val.y += kb * xv.y;
                val.z += kb * xv.z; val.w += kb * xv.w;
            }
        }
        float* dst = lt + (vv * 8 + si) * 65 + c4;
        dst[0] = val.x; dst[1] = val.y; dst[2] = val.z; dst[3] = val.w;
    }
    __syncthreads();
    // transposed store: thread (si, vv) fixed (one div per thread), loop d
    if (tid < 200) {
        int si = tid / 25, vv = tid - si * 25;
        const float* src = lt + (vv * 8 + si) * 65;
        float* ob = out + (size_t)n * (C_ * S_ * V_) + (size_t)(s0 + si) * V_ + vv;
        #pragma unroll 8
        for (int d = 0; d < C_; ++d)
            ob[(size_t)d * (S_ * V_)] = src[d];
    }
}

// -----------------------------------------------------------------------------
extern "C" void kernel_launch(void* const* d_in, const int* in_sizes, int n_in,
                              void* d_out, int out_size, void* d_ws, size_t ws_size,
                              hipStream_t stream)
{
    const float* x     = (const float*)d_in[0];
    const float* W     = (const float*)d_in[1];
    const float* alpha = (const float*)d_in[2];
    const float* phi   = (const float*)d_in[3];
    const float* kband = (const float*)d_in[4];

    float* xp  = (float*)d_ws;                       // 52,428,800 B
    float* tmp = xp + (size_t)N_ * M_ * C_;          // 26,214,400 B (total 78.6 MB)

    xp_gemm_kernel<<<dim3(M_ / 256, N_), 256, 0, stream>>>(x, W, xp);
    attn_kernel<<<dim3(N_ * V_), 512, 0, stream>>>(xp, alpha, phi, tmp);
    final_kernel<<<dim3(N_ * 32), 256, 0, stream>>>(tmp, xp, kband, (float*)d_out);
}